// Round 18
// baseline (479.567 us; speedup 1.0000x reference)
//
#include <hip/hip_runtime.h>
#include <hip/hip_bf16.h>
#include <cstdint>

// Block: B=4, S=2048, E=1024, H=16, DH=64, DF=4096.  M = B*S = 8192 rows.
// All GEMMs: unified gemmU -- 128x128 tile, BK=64, 4 waves (2Mx2N) of 64x64,
// reg-cached fragments, 8-chunk XOR swizzle (0 conflicts), dbuf 64 KB ->
// 2 blocks/CU.  FFN B = W1|W2 16-col interleave (SwiGLU fused).
// Attention v4.3: P-scratch carved out of the dead Kb[cur] tile (raw
// s_barrier between QK-reads and P-writes; no vmcnt drain) -> LDS 32 KB ->
// 5 blocks/CU (20 waves, +25% latency hiding for this latency-bound kernel).

typedef __bf16 bf16_t;
typedef __attribute__((ext_vector_type(8))) __bf16 bf16x8;
typedef __attribute__((ext_vector_type(4))) __bf16 bf16x4;
typedef __attribute__((ext_vector_type(4))) float f32x4;

#define LOG2E 1.4426950408889634f

static __device__ __forceinline__ void gll16(const void* g, void* l) {
  __builtin_amdgcn_global_load_lds(
      (const __attribute__((address_space(1))) void*)g,
      (__attribute__((address_space(3))) void*)l, 16, 0, 0);
}

// ---------------- transpose + fp32->bf16 convert (+optional scale) ---------
template<int PACK>
__global__ __launch_bounds__(256)
void transpose_cvt(const float* __restrict__ in, bf16_t* __restrict__ out,
                   int R, int C, long in_batch, long out_batch, int off,
                   float scale)
{
  __shared__ float tile[64][65];
  const float* inp = in + (long)blockIdx.z * in_batch;
  bf16_t* outp = out + (long)blockIdx.z * out_batch;
  const int c0 = blockIdx.x * 64, r0 = blockIdx.y * 64;
  for (int rr = threadIdx.y; rr < 64; rr += 4)
    tile[rr][threadIdx.x] = inp[(long)(r0 + rr) * C + c0 + threadIdx.x];
  __syncthreads();
  for (int cc = threadIdx.y; cc < 64; cc += 4) {
    const int c = c0 + cc;
    const long orow = PACK ? (long)((c >> 4) * 32 + (c & 15) + off) : (long)c;
    outp[orow * R + r0 + threadIdx.x] = (bf16_t)(tile[threadIdx.x][cc] * scale);
  }
}

// ---------------- LayerNorm (fp32/bf16 in, bf16 out) ----------------
template<int BF16IN>
__global__ __launch_bounds__(256)
void ln_kernel(const void* __restrict__ xin, const float* __restrict__ g,
               const float* __restrict__ be, bf16_t* __restrict__ out)
{
  const long row = blockIdx.x;
  float e0, e1, e2, e3;
  if constexpr (BF16IN) {
    const bf16x4 v = ((const bf16x4*)((const bf16_t*)xin + row * 1024))[threadIdx.x];
    e0 = (float)v[0]; e1 = (float)v[1]; e2 = (float)v[2]; e3 = (float)v[3];
  } else {
    const float4 v = ((const float4*)((const float*)xin + row * 1024))[threadIdx.x];
    e0 = v.x; e1 = v.y; e2 = v.z; e3 = v.w;
  }
  float s  = e0 + e1 + e2 + e3;
  float s2 = e0*e0 + e1*e1 + e2*e2 + e3*e3;
  #pragma unroll
  for (int m = 1; m < 64; m <<= 1) {
    s  += __shfl_xor(s, m, 64);
    s2 += __shfl_xor(s2, m, 64);
  }
  __shared__ float red[8];
  const int w = threadIdx.x >> 6, lane = threadIdx.x & 63;
  if (lane == 0) { red[w] = s; red[4 + w] = s2; }
  __syncthreads();
  s  = red[0] + red[1] + red[2] + red[3];
  s2 = red[4] + red[5] + red[6] + red[7];
  const float mu = s * (1.f / 1024.f);
  const float rs = rsqrtf(s2 * (1.f / 1024.f) - mu * mu + 1e-5f);
  const int c = threadIdx.x * 4;
  bf16x4 o;
  o[0] = (bf16_t)((e0 - mu) * rs * g[c+0] + be[c+0]);
  o[1] = (bf16_t)((e1 - mu) * rs * g[c+1] + be[c+1]);
  o[2] = (bf16_t)((e2 - mu) * rs * g[c+2] + be[c+2]);
  o[3] = (bf16_t)((e3 - mu) * rs * g[c+3] + be[c+3]);
  *(bf16x4*)(out + row * 1024 + c) = o;
}

// ================= unified 128x128 GEMM, BK=64, 4 waves, 2 blocks/CU =======
template<int EPI, int KT>
__global__ __launch_bounds__(256, 2)
void gemmU(const bf16_t* __restrict__ A, const bf16_t* __restrict__ Bt,
           const float* __restrict__ bias, const float* __restrict__ bias2,
           const float* __restrict__ resF, const bf16_t* __restrict__ resB,
           float* __restrict__ outF, bf16_t* __restrict__ outB,
           bf16_t* __restrict__ outQ, bf16_t* __restrict__ outK, bf16_t* __restrict__ outV,
           int N)
{
  __shared__ __align__(16) bf16_t Asl[2][128 * 64];
  __shared__ __align__(16) bf16_t Bsl[2][128 * 64];
  constexpr int NT = KT / 64;
  const int tid = threadIdx.x, lane = tid & 63;
  const int w = tid >> 6, wr = w >> 1, wc = w & 1;
  const long row0 = (long)blockIdx.y * 128;
  const long col0 = (long)blockIdx.x * 128;
  const int l15 = lane & 15, lhi = lane >> 4;
  const int offk0 = ((lhi ^ (l15 & 7)) & 7) * 8;   // swizzled chunk, ks=0
  f32x4 acc[4][4] = {};

  auto stage = [&](int t, int buf) {     // 8 gll16/thread: A 16KB + B 16KB
    const long k0 = (long)t * 64;
    #pragma unroll
    for (int i = 0; i < 4; ++i) {
      const int p = tid + 256 * i;
      const int r = p >> 3, cl = (p & 7) ^ (r & 7);
      gll16(A + (row0 + r) * (long)KT + k0 + cl * 8, (char*)Asl[buf] + p * 16);
    }
    #pragma unroll
    for (int i = 0; i < 4; ++i) {
      const int p = tid + 256 * i;
      const int r = p >> 3, cl = (p & 7) ^ (r & 7);
      gll16(Bt + (col0 + r) * (long)KT + k0 + cl * 8, (char*)Bsl[buf] + p * 16);
    }
  };

  stage(0, 0);
  __syncthreads();
  int cur = 0;
  for (int t = 0; t < NT; ++t) {
    if (t + 1 < NT) stage(t + 1, cur ^ 1);
    bf16x8 af[4][2], bfr[4][2];
    const bf16_t* ap = Asl[cur] + (wr * 64 + l15) * 64;
    const bf16_t* bp = Bsl[cur] + (wc * 64 + l15) * 64;
    #pragma unroll
    for (int m = 0; m < 4; ++m) {
      af[m][0] = *(const bf16x8*)(ap + m * 16 * 64 + offk0);
      af[m][1] = *(const bf16x8*)(ap + m * 16 * 64 + (offk0 ^ 32));
    }
    #pragma unroll
    for (int n = 0; n < 4; ++n) {
      bfr[n][0] = *(const bf16x8*)(bp + n * 16 * 64 + offk0);
      bfr[n][1] = *(const bf16x8*)(bp + n * 16 * 64 + (offk0 ^ 32));
    }
    __builtin_amdgcn_s_setprio(1);
    #pragma unroll
    for (int m = 0; m < 4; ++m)
      #pragma unroll
      for (int n = 0; n < 4; ++n)
        #pragma unroll
        for (int ks = 0; ks < 2; ++ks)
          acc[m][n] = __builtin_amdgcn_mfma_f32_16x16x32_bf16(
              af[m][ks], bfr[n][ks], acc[m][n], 0, 0, 0);
    __builtin_amdgcn_s_setprio(0);
    __syncthreads();
    cur ^= 1;
  }

  if constexpr (EPI == 3) {
    const long L0 = ((col0 + wc * 64) >> 5) * 16;
    #pragma unroll
    for (int m = 0; m < 4; ++m) {
      #pragma unroll
      for (int np = 0; np < 2; ++np) {
        const long lc = L0 + np * 16 + l15;
        #pragma unroll
        for (int r = 0; r < 4; ++r) {
          const long rr = row0 + wr * 64 + m * 16 + lhi * 4 + r;
          const float a  = acc[m][2 * np][r] + bias[lc];
          const float gt = acc[m][2 * np + 1][r] + bias2[lc];
          const float sig = 1.0f / (1.0f + __expf(-a));
          outB[rr * N + lc] = (bf16_t)(a * sig * gt);
        }
      }
    }
  } else {
    #pragma unroll
    for (int m = 0; m < 4; ++m) {
      #pragma unroll
      for (int n = 0; n < 4; ++n) {
        const long cc = col0 + wc * 64 + n * 16 + l15;
        #pragma unroll
        for (int r = 0; r < 4; ++r) {
          const long rr = row0 + wr * 64 + m * 16 + lhi * 4 + r;
          const float v = acc[m][n][r];
          if constexpr (EPI == 0) {
            const int which = (int)(cc >> 10);
            const int hh = (int)((cc >> 6) & 15);
            const int d  = (int)(cc & 63);
            const long b = rr >> 11, s2 = rr & 2047;
            const bf16_t bv = (bf16_t)v;
            const long bh = b * 16 + hh;
            if (which == 0)      outQ[(bh * 2048 + s2) * 64 + d] = bv;
            else if (which == 1) outK[(bh * 2048 + s2) * 64 + d] = bv;
            else                 outV[(bh * 64 + d) * 2048 + s2] = bv;
          } else if constexpr (EPI == 1) {
            outB[rr * N + cc] = (bf16_t)(v + bias[cc] + resF[rr * N + cc]);
          } else {
            outF[rr * N + cc] = v + bias[cc] + (float)resB[rr * N + cc];
          }
        }
      }
    }
  }
}

// ---------------- causal flash attention v4.3 ------------------------------
// Scale folded into Wq; defer-max; fma exp2; tree max-reduce (all R17).
// NEW: P-scratch lives in the dead Kb[cur] tile (per-wave 2 KB quarter).
// Raw s_barrier (NO vmcnt drain -- K/V DMA stays in flight) between QK-reads
// and P-writes; kf reads are data-complete via the QK MFMA dependency.
// LDS 32 KB -> 5 blocks/CU (20 waves).
__global__ __launch_bounds__(256, 5)
void attn_kernel(const bf16_t* __restrict__ q, const bf16_t* __restrict__ k,
                 const bf16_t* __restrict__ vT, bf16_t* __restrict__ ctx)
{
  __shared__ __align__(16) bf16_t Kb[2][64 * 64];
  __shared__ __align__(16) bf16_t Vb[2][64 * 64];
  const int tid = threadIdx.x, lane = tid & 63, wvi = tid >> 6;
  const int bh = blockIdx.x;
  const bf16_t* qp = q  + (long)bh * 2048 * 64;
  const bf16_t* kp = k  + (long)bh * 2048 * 64;
  const bf16_t* vp = vT + (long)bh * 64 * 2048;
  const int l15 = lane & 15, lhi = lane >> 4;
  const long b = bh >> 4;
  const int hh = bh & 15;
  const int sw = (l15 & 7);
  const int psw = sw << 1;

  const int r0s = tid >> 3, cl0 = (tid & 7) ^ (r0s & 7);
  const int r1s = (tid + 256) >> 3, cl1 = (tid & 7) ^ (r1s & 7);

  #pragma unroll
  for (int seg = 0; seg < 2; ++seg) {
    const int ts = (seg == 0) ? blockIdx.y : 31 - blockIdx.y;
    const int qw0 = ts * 64 + wvi * 16;
    const int q_glob = qw0 + l15;
    bf16x8 qf[2];
    #pragma unroll
    for (int kk = 0; kk < 2; ++kk)
      qf[kk] = *(const bf16x8*)(qp + (long)(qw0 + l15) * 64 + kk * 32 + lhi * 8);
    f32x4 accO[4] = {};
    float mrow = -1e30f, lrow = 0.f;

    gll16(kp + (long)(0 + r0s) * 64 + cl0 * 8, (char*)Kb[0] + tid * 16);
    gll16(vp + (long)r0s * 2048 + 0 + cl0 * 8, (char*)Vb[0] + tid * 16);
    gll16(kp + (long)(0 + r1s) * 64 + cl1 * 8, (char*)Kb[0] + (tid + 256) * 16);
    gll16(vp + (long)r1s * 2048 + 0 + cl1 * 8, (char*)Vb[0] + (tid + 256) * 16);
    __syncthreads();

    int cur = 0;
    const int kbmax = ts * 64;
    for (int kb = 0; kb <= kbmax; kb += 64) {
      if (kb + 64 <= kbmax) {
        const int nb = kb + 64;
        gll16(kp + (long)(nb + r0s) * 64 + cl0 * 8, (char*)Kb[cur ^ 1] + tid * 16);
        gll16(vp + (long)r0s * 2048 + nb + cl0 * 8, (char*)Vb[cur ^ 1] + tid * 16);
        gll16(kp + (long)(nb + r1s) * 64 + cl1 * 8, (char*)Kb[cur ^ 1] + (tid + 256) * 16);
        gll16(vp + (long)r1s * 2048 + nb + cl1 * 8, (char*)Vb[cur ^ 1] + (tid + 256) * 16);
      }
      f32x4 accS[4] = {};
      #pragma unroll
      for (int n = 0; n < 4; ++n) {
        const bf16_t* kr = Kb[cur] + (n * 16 + l15) * 64;
        #pragma unroll
        for (int kk = 0; kk < 2; ++kk) {
          const bf16x8 kf = *(const bf16x8*)(kr + ((kk * 4 + lhi) ^ sw) * 8);
          accS[n] = __builtin_amdgcn_mfma_f32_16x16x32_bf16(kf, qf[kk], accS[n], 0, 0, 0);
        }
      }
      const bool needmask = (kb + 63 > qw0);
      if (needmask) {
        #pragma unroll
        for (int n = 0; n < 4; ++n)
          #pragma unroll
          for (int r = 0; r < 4; ++r)
            if (kb + n * 16 + lhi * 4 + r > q_glob) accS[n][r] = -1e30f;
      }
      float t0 = fmaxf(fmaxf(accS[0][0], accS[0][1]), fmaxf(accS[0][2], accS[0][3]));
      float t1 = fmaxf(fmaxf(accS[1][0], accS[1][1]), fmaxf(accS[1][2], accS[1][3]));
      float t2 = fmaxf(fmaxf(accS[2][0], accS[2][1]), fmaxf(accS[2][2], accS[2][3]));
      float t3 = fmaxf(fmaxf(accS[3][0], accS[3][1]), fmaxf(accS[3][2], accS[3][3]));
      float rmax = fmaxf(fmaxf(t0, t1), fmaxf(t2, t3));
      rmax = fmaxf(rmax, __shfl_xor(rmax, 16, 64));
      rmax = fmaxf(rmax, __shfl_xor(rmax, 32, 64));
      float corr = 1.f;
      if (__any(rmax > mrow)) {
        const float mn = fmaxf(mrow, rmax);
        corr = exp2f((mrow - mn) * LOG2E);
        mrow = mn;
        #pragma unroll
        for (int nd = 0; nd < 4; ++nd)
          #pragma unroll
          for (int r = 0; r < 4; ++r) accO[nd][r] *= corr;
      }
      const float mb = mrow * LOG2E;
      float rsum = 0.f;
      #pragma unroll
      for (int n = 0; n < 4; ++n)
        #pragma unroll
        for (int r = 0; r < 4; ++r) {
          const float p = exp2f(fmaf(accS[n][r], LOG2E, -mb));
          accS[n][r] = p;
          rsum += p;
        }
      rsum += __shfl_xor(rsum, 16, 64);
      rsum += __shfl_xor(rsum, 32, 64);
      lrow = lrow * corr + rsum;
      // ---- all waves' kf reads are complete (QK MFMA data dependency);
      // raw barrier (no vmcnt drain) before overwriting Kb[cur] with P.
      __builtin_amdgcn_sched_barrier(0);
      __builtin_amdgcn_s_barrier();
      __builtin_amdgcn_sched_barrier(0);
      bf16_t* pq = Kb[cur] + wvi * 1024;   // this wave's 2 KB quarter
      #pragma unroll
      for (int n = 0; n < 4; ++n) {
        bf16x4 pk;
        #pragma unroll
        for (int r = 0; r < 4; ++r) pk[r] = (bf16_t)accS[n][r];
        *(bf16x4*)(&pq[l15 * 64 + ((4 * n + lhi) ^ psw) * 4]) = pk;
      }
      #pragma unroll
      for (int kk = 0; kk < 2; ++kk) {
        const bf16x8 pf = *(const bf16x8*)(&pq[l15 * 64 + ((8 * kk + 2 * lhi) ^ psw) * 4]);
        #pragma unroll
        for (int nd = 0; nd < 4; ++nd) {
          const bf16x8 vf = *(const bf16x8*)(Vb[cur] + (nd * 16 + l15) * 64 + ((kk * 4 + lhi) ^ sw) * 8);
          accO[nd] = __builtin_amdgcn_mfma_f32_16x16x32_bf16(vf, pf, accO[nd], 0, 0, 0);
        }
      }
      __syncthreads();
      cur ^= 1;
    }
    const float inv = 1.f / lrow;
    const long crow = (b * 2048 + qw0 + l15) * 1024 + hh * 64;
    #pragma unroll
    for (int nd = 0; nd < 4; ++nd) {
      bf16x4 ok;
      #pragma unroll
      for (int r = 0; r < 4; ++r) ok[r] = (bf16_t)(accO[nd][r] * inv);
      *(bf16x4*)(ctx + crow + nd * 16 + lhi * 4) = ok;
    }
  }
}

extern "C" void kernel_launch(void* const* d_in, const int* in_sizes, int n_in,
                              void* d_out, int out_size, void* d_ws, size_t ws_size,
                              hipStream_t stream)
{
  const float* x   = (const float*)d_in[0];
  const float* wq  = (const float*)d_in[1];
  const float* wk  = (const float*)d_in[2];
  const float* wv  = (const float*)d_in[3];
  const float* wo  = (const float*)d_in[4];
  const float* bo  = (const float*)d_in[5];
  const float* w1  = (const float*)d_in[6];
  const float* b1  = (const float*)d_in[7];
  const float* w2  = (const float*)d_in[8];
  const float* b2  = (const float*)d_in[9];
  const float* w3  = (const float*)d_in[10];
  const float* b3  = (const float*)d_in[11];
  const float* g1  = (const float*)d_in[12];
  const float* be1 = (const float*)d_in[13];
  const float* g2  = (const float*)d_in[14];
  const float* be2 = (const float*)d_in[15];
  float* out = (float*)d_out;

  char* ws = (char*)d_ws;
  bf16_t* h    = (bf16_t*)(ws);                          // 16 MiB (later: ctx)
  bf16_t* qb   = (bf16_t*)(ws + 16777216L);              // 16 MiB (later: h2)
  bf16_t* kb   = (bf16_t*)(ws + 2 * 16777216L);          // 16 MiB
  bf16_t* vTb  = (bf16_t*)(ws + 3 * 16777216L);          // 16 MiB
  bf16_t* r1b  = (bf16_t*)(ws + 4 * 16777216L);          // 16 MiB (bf16 residual)
  bf16_t* ffin = (bf16_t*)(ws + 4 * 16777216L + 33554432L); // 64 MiB
  char* wbase  = ws + 4 * 16777216L + 33554432L + 67108864L;
  bf16_t* Wqkvt = (bf16_t*)(wbase);                      // [3072][1024]
  bf16_t* Wot   = (bf16_t*)(wbase + 6291456L);           // [1024][1024]
  bf16_t* Wp    = (bf16_t*)(wbase + 8388608L);           // [8192][1024] packed W1|W2
  bf16_t* W3t   = (bf16_t*)(wbase + 25165824L);          // [1024][4096]

  const dim3 tb(64, 4);
  transpose_cvt<0><<<dim3(1, 16, 16), tb, 0, stream>>>(wq, Wqkvt,            1024, 64, 65536, 65536, 0, 0.125f);
  transpose_cvt<0><<<dim3(1, 16, 16), tb, 0, stream>>>(wk, Wqkvt + 1048576L, 1024, 64, 65536, 65536, 0, 1.0f);
  transpose_cvt<0><<<dim3(1, 16, 16), tb, 0, stream>>>(wv, Wqkvt + 2097152L, 1024, 64, 65536, 65536, 0, 1.0f);
  transpose_cvt<0><<<dim3(16, 16, 1), tb, 0, stream>>>(wo, Wot, 1024, 1024, 0, 0, 0, 1.0f);
  transpose_cvt<1><<<dim3(64, 16, 1), tb, 0, stream>>>(w1, Wp, 1024, 4096, 0, 0, 0, 1.0f);
  transpose_cvt<1><<<dim3(64, 16, 1), tb, 0, stream>>>(w2, Wp, 1024, 4096, 0, 0, 16, 1.0f);
  transpose_cvt<0><<<dim3(16, 64, 1), tb, 0, stream>>>(w3, W3t, 4096, 1024, 0, 0, 0, 1.0f);
  // LN1
  ln_kernel<0><<<8192, 256, 0, stream>>>(x, g1, be1, h);
  // QKV projection
  gemmU<0, 1024><<<dim3(24, 64), 256, 0, stream>>>(h, Wqkvt, nullptr, nullptr, nullptr, nullptr,
                                                   nullptr, nullptr, qb, kb, vTb, 3072);
  // attention -> ctx (reuses h)
  attn_kernel<<<dim3(64, 16), 256, 0, stream>>>(qb, kb, vTb, h);
  // r1b (bf16) = x + ctx @ Wo + bo
  gemmU<1, 1024><<<dim3(8, 64), 256, 0, stream>>>(h, Wot, bo, nullptr, x, nullptr,
                                                  nullptr, r1b, nullptr, nullptr, nullptr, 1024);
  // LN2 -> h2 (reuses qb)
  ln_kernel<1><<<8192, 256, 0, stream>>>(r1b, g2, be2, qb);
  // ffin = silu(h2@W1+b1) * (h2@W2+b2)  -- packed dual, logical N = 4096
  gemmU<3, 1024><<<dim3(64, 64), 256, 0, stream>>>(qb, Wp, b1, b2, nullptr, nullptr,
                                                   nullptr, ffin, nullptr, nullptr, nullptr, 4096);
  // out (fp32) = r1b + ffin @ w3 + b3
  gemmU<2, 4096><<<dim3(8, 64), 256, 0, stream>>>(ffin, W3t, b3, nullptr, nullptr, r1b,
                                                  out, nullptr, nullptr, nullptr, nullptr, 1024);
}

// Round 19
// 473.449 us; speedup vs baseline: 1.0129x; 1.0129x over previous
//
#include <hip/hip_runtime.h>
#include <hip/hip_bf16.h>
#include <cstdint>

// Block: B=4, S=2048, E=1024, H=16, DH=64, DF=4096.  M = B*S = 8192 rows.
// All GEMMs: unified gemmU -- 128x128 tile, BK=64, 4 waves (2Mx2N) of 64x64,
// reg-cached fragments, 8-chunk XOR swizzle (0 conflicts), dbuf 64 KB ->
// 2 blocks/CU.  FFN B = W1|W2 16-col interleave (SwiGLU fused).
// Attention: 4-wave 64-row kernel (R17 best), K/V LDS-staged, 4 blocks/CU;
// scale-folded-into-Wq, defer-max skip, fma-folded exp2, tree max-reduce.

typedef __bf16 bf16_t;
typedef __attribute__((ext_vector_type(8))) __bf16 bf16x8;
typedef __attribute__((ext_vector_type(4))) __bf16 bf16x4;
typedef __attribute__((ext_vector_type(4))) float f32x4;

#define LOG2E 1.4426950408889634f

static __device__ __forceinline__ void gll16(const void* g, void* l) {
  __builtin_amdgcn_global_load_lds(
      (const __attribute__((address_space(1))) void*)g,
      (__attribute__((address_space(3))) void*)l, 16, 0, 0);
}

// ---------------- transpose + fp32->bf16 convert (+optional scale) ---------
template<int PACK>
__global__ __launch_bounds__(256)
void transpose_cvt(const float* __restrict__ in, bf16_t* __restrict__ out,
                   int R, int C, long in_batch, long out_batch, int off,
                   float scale)
{
  __shared__ float tile[64][65];
  const float* inp = in + (long)blockIdx.z * in_batch;
  bf16_t* outp = out + (long)blockIdx.z * out_batch;
  const int c0 = blockIdx.x * 64, r0 = blockIdx.y * 64;
  for (int rr = threadIdx.y; rr < 64; rr += 4)
    tile[rr][threadIdx.x] = inp[(long)(r0 + rr) * C + c0 + threadIdx.x];
  __syncthreads();
  for (int cc = threadIdx.y; cc < 64; cc += 4) {
    const int c = c0 + cc;
    const long orow = PACK ? (long)((c >> 4) * 32 + (c & 15) + off) : (long)c;
    outp[orow * R + r0 + threadIdx.x] = (bf16_t)(tile[threadIdx.x][cc] * scale);
  }
}

// ---------------- LayerNorm (fp32/bf16 in, bf16 out) ----------------
template<int BF16IN>
__global__ __launch_bounds__(256)
void ln_kernel(const void* __restrict__ xin, const float* __restrict__ g,
               const float* __restrict__ be, bf16_t* __restrict__ out)
{
  const long row = blockIdx.x;
  float e0, e1, e2, e3;
  if constexpr (BF16IN) {
    const bf16x4 v = ((const bf16x4*)((const bf16_t*)xin + row * 1024))[threadIdx.x];
    e0 = (float)v[0]; e1 = (float)v[1]; e2 = (float)v[2]; e3 = (float)v[3];
  } else {
    const float4 v = ((const float4*)((const float*)xin + row * 1024))[threadIdx.x];
    e0 = v.x; e1 = v.y; e2 = v.z; e3 = v.w;
  }
  float s  = e0 + e1 + e2 + e3;
  float s2 = e0*e0 + e1*e1 + e2*e2 + e3*e3;
  #pragma unroll
  for (int m = 1; m < 64; m <<= 1) {
    s  += __shfl_xor(s, m, 64);
    s2 += __shfl_xor(s2, m, 64);
  }
  __shared__ float red[8];
  const int w = threadIdx.x >> 6, lane = threadIdx.x & 63;
  if (lane == 0) { red[w] = s; red[4 + w] = s2; }
  __syncthreads();
  s  = red[0] + red[1] + red[2] + red[3];
  s2 = red[4] + red[5] + red[6] + red[7];
  const float mu = s * (1.f / 1024.f);
  const float rs = rsqrtf(s2 * (1.f / 1024.f) - mu * mu + 1e-5f);
  const int c = threadIdx.x * 4;
  bf16x4 o;
  o[0] = (bf16_t)((e0 - mu) * rs * g[c+0] + be[c+0]);
  o[1] = (bf16_t)((e1 - mu) * rs * g[c+1] + be[c+1]);
  o[2] = (bf16_t)((e2 - mu) * rs * g[c+2] + be[c+2]);
  o[3] = (bf16_t)((e3 - mu) * rs * g[c+3] + be[c+3]);
  *(bf16x4*)(out + row * 1024 + c) = o;
}

// ================= unified 128x128 GEMM, BK=64, 4 waves, 2 blocks/CU =======
template<int EPI, int KT>
__global__ __launch_bounds__(256, 2)
void gemmU(const bf16_t* __restrict__ A, const bf16_t* __restrict__ Bt,
           const float* __restrict__ bias, const float* __restrict__ bias2,
           const float* __restrict__ resF, const bf16_t* __restrict__ resB,
           float* __restrict__ outF, bf16_t* __restrict__ outB,
           bf16_t* __restrict__ outQ, bf16_t* __restrict__ outK, bf16_t* __restrict__ outV,
           int N)
{
  __shared__ __align__(16) bf16_t Asl[2][128 * 64];
  __shared__ __align__(16) bf16_t Bsl[2][128 * 64];
  constexpr int NT = KT / 64;
  const int tid = threadIdx.x, lane = tid & 63;
  const int w = tid >> 6, wr = w >> 1, wc = w & 1;
  const long row0 = (long)blockIdx.y * 128;
  const long col0 = (long)blockIdx.x * 128;
  const int l15 = lane & 15, lhi = lane >> 4;
  const int offk0 = ((lhi ^ (l15 & 7)) & 7) * 8;   // swizzled chunk, ks=0
  f32x4 acc[4][4] = {};

  auto stage = [&](int t, int buf) {     // 8 gll16/thread: A 16KB + B 16KB
    const long k0 = (long)t * 64;
    #pragma unroll
    for (int i = 0; i < 4; ++i) {
      const int p = tid + 256 * i;
      const int r = p >> 3, cl = (p & 7) ^ (r & 7);
      gll16(A + (row0 + r) * (long)KT + k0 + cl * 8, (char*)Asl[buf] + p * 16);
    }
    #pragma unroll
    for (int i = 0; i < 4; ++i) {
      const int p = tid + 256 * i;
      const int r = p >> 3, cl = (p & 7) ^ (r & 7);
      gll16(Bt + (col0 + r) * (long)KT + k0 + cl * 8, (char*)Bsl[buf] + p * 16);
    }
  };

  stage(0, 0);
  __syncthreads();
  int cur = 0;
  for (int t = 0; t < NT; ++t) {
    if (t + 1 < NT) stage(t + 1, cur ^ 1);
    bf16x8 af[4][2], bfr[4][2];
    const bf16_t* ap = Asl[cur] + (wr * 64 + l15) * 64;
    const bf16_t* bp = Bsl[cur] + (wc * 64 + l15) * 64;
    #pragma unroll
    for (int m = 0; m < 4; ++m) {
      af[m][0] = *(const bf16x8*)(ap + m * 16 * 64 + offk0);
      af[m][1] = *(const bf16x8*)(ap + m * 16 * 64 + (offk0 ^ 32));
    }
    #pragma unroll
    for (int n = 0; n < 4; ++n) {
      bfr[n][0] = *(const bf16x8*)(bp + n * 16 * 64 + offk0);
      bfr[n][1] = *(const bf16x8*)(bp + n * 16 * 64 + (offk0 ^ 32));
    }
    __builtin_amdgcn_s_setprio(1);
    #pragma unroll
    for (int m = 0; m < 4; ++m)
      #pragma unroll
      for (int n = 0; n < 4; ++n)
        #pragma unroll
        for (int ks = 0; ks < 2; ++ks)
          acc[m][n] = __builtin_amdgcn_mfma_f32_16x16x32_bf16(
              af[m][ks], bfr[n][ks], acc[m][n], 0, 0, 0);
    __builtin_amdgcn_s_setprio(0);
    __syncthreads();
    cur ^= 1;
  }

  if constexpr (EPI == 3) {
    const long L0 = ((col0 + wc * 64) >> 5) * 16;
    #pragma unroll
    for (int m = 0; m < 4; ++m) {
      #pragma unroll
      for (int np = 0; np < 2; ++np) {
        const long lc = L0 + np * 16 + l15;
        #pragma unroll
        for (int r = 0; r < 4; ++r) {
          const long rr = row0 + wr * 64 + m * 16 + lhi * 4 + r;
          const float a  = acc[m][2 * np][r] + bias[lc];
          const float gt = acc[m][2 * np + 1][r] + bias2[lc];
          const float sig = 1.0f / (1.0f + __expf(-a));
          outB[rr * N + lc] = (bf16_t)(a * sig * gt);
        }
      }
    }
  } else {
    #pragma unroll
    for (int m = 0; m < 4; ++m) {
      #pragma unroll
      for (int n = 0; n < 4; ++n) {
        const long cc = col0 + wc * 64 + n * 16 + l15;
        #pragma unroll
        for (int r = 0; r < 4; ++r) {
          const long rr = row0 + wr * 64 + m * 16 + lhi * 4 + r;
          const float v = acc[m][n][r];
          if constexpr (EPI == 0) {
            const int which = (int)(cc >> 10);
            const int hh = (int)((cc >> 6) & 15);
            const int d  = (int)(cc & 63);
            const long b = rr >> 11, s2 = rr & 2047;
            const bf16_t bv = (bf16_t)v;
            const long bh = b * 16 + hh;
            if (which == 0)      outQ[(bh * 2048 + s2) * 64 + d] = bv;
            else if (which == 1) outK[(bh * 2048 + s2) * 64 + d] = bv;
            else                 outV[(bh * 64 + d) * 2048 + s2] = bv;
          } else if constexpr (EPI == 1) {
            outB[rr * N + cc] = (bf16_t)(v + bias[cc] + resF[rr * N + cc]);
          } else {
            outF[rr * N + cc] = v + bias[cc] + (float)resB[rr * N + cc];
          }
        }
      }
    }
  }
}

// ---------------- causal flash attention v4.2 (R17 best) -------------------
__global__ __launch_bounds__(256, 4)
void attn_kernel(const bf16_t* __restrict__ q, const bf16_t* __restrict__ k,
                 const bf16_t* __restrict__ vT, bf16_t* __restrict__ ctx)
{
  __shared__ __align__(16) bf16_t Kb[2][64 * 64];
  __shared__ __align__(16) bf16_t Vb[2][64 * 64];
  __shared__ __align__(16) bf16_t plds[4][16 * 64];
  const int tid = threadIdx.x, lane = tid & 63, wvi = tid >> 6;
  const int bh = blockIdx.x;
  const bf16_t* qp = q  + (long)bh * 2048 * 64;
  const bf16_t* kp = k  + (long)bh * 2048 * 64;
  const bf16_t* vp = vT + (long)bh * 64 * 2048;
  const int l15 = lane & 15, lhi = lane >> 4;
  const long b = bh >> 4;
  const int hh = bh & 15;
  const int sw = (l15 & 7);
  const int psw = sw << 1;

  const int r0s = tid >> 3, cl0 = (tid & 7) ^ (r0s & 7);
  const int r1s = (tid + 256) >> 3, cl1 = (tid & 7) ^ (r1s & 7);

  #pragma unroll
  for (int seg = 0; seg < 2; ++seg) {
    const int ts = (seg == 0) ? blockIdx.y : 31 - blockIdx.y;
    const int qw0 = ts * 64 + wvi * 16;
    const int q_glob = qw0 + l15;
    bf16x8 qf[2];
    #pragma unroll
    for (int kk = 0; kk < 2; ++kk)
      qf[kk] = *(const bf16x8*)(qp + (long)(qw0 + l15) * 64 + kk * 32 + lhi * 8);
    f32x4 accO[4] = {};
    float mrow = -1e30f, lrow = 0.f;

    gll16(kp + (long)(0 + r0s) * 64 + cl0 * 8, (char*)Kb[0] + tid * 16);
    gll16(vp + (long)r0s * 2048 + 0 + cl0 * 8, (char*)Vb[0] + tid * 16);
    gll16(kp + (long)(0 + r1s) * 64 + cl1 * 8, (char*)Kb[0] + (tid + 256) * 16);
    gll16(vp + (long)r1s * 2048 + 0 + cl1 * 8, (char*)Vb[0] + (tid + 256) * 16);
    __syncthreads();

    int cur = 0;
    const int kbmax = ts * 64;
    for (int kb = 0; kb <= kbmax; kb += 64) {
      if (kb + 64 <= kbmax) {
        const int nb = kb + 64;
        gll16(kp + (long)(nb + r0s) * 64 + cl0 * 8, (char*)Kb[cur ^ 1] + tid * 16);
        gll16(vp + (long)r0s * 2048 + nb + cl0 * 8, (char*)Vb[cur ^ 1] + tid * 16);
        gll16(kp + (long)(nb + r1s) * 64 + cl1 * 8, (char*)Kb[cur ^ 1] + (tid + 256) * 16);
        gll16(vp + (long)r1s * 2048 + nb + cl1 * 8, (char*)Vb[cur ^ 1] + (tid + 256) * 16);
      }
      f32x4 accS[4] = {};
      #pragma unroll
      for (int n = 0; n < 4; ++n) {
        const bf16_t* kr = Kb[cur] + (n * 16 + l15) * 64;
        #pragma unroll
        for (int kk = 0; kk < 2; ++kk) {
          const bf16x8 kf = *(const bf16x8*)(kr + ((kk * 4 + lhi) ^ sw) * 8);
          accS[n] = __builtin_amdgcn_mfma_f32_16x16x32_bf16(kf, qf[kk], accS[n], 0, 0, 0);
        }
      }
      const bool needmask = (kb + 63 > qw0);
      if (needmask) {
        #pragma unroll
        for (int n = 0; n < 4; ++n)
          #pragma unroll
          for (int r = 0; r < 4; ++r)
            if (kb + n * 16 + lhi * 4 + r > q_glob) accS[n][r] = -1e30f;
      }
      float t0 = fmaxf(fmaxf(accS[0][0], accS[0][1]), fmaxf(accS[0][2], accS[0][3]));
      float t1 = fmaxf(fmaxf(accS[1][0], accS[1][1]), fmaxf(accS[1][2], accS[1][3]));
      float t2 = fmaxf(fmaxf(accS[2][0], accS[2][1]), fmaxf(accS[2][2], accS[2][3]));
      float t3 = fmaxf(fmaxf(accS[3][0], accS[3][1]), fmaxf(accS[3][2], accS[3][3]));
      float rmax = fmaxf(fmaxf(t0, t1), fmaxf(t2, t3));
      rmax = fmaxf(rmax, __shfl_xor(rmax, 16, 64));
      rmax = fmaxf(rmax, __shfl_xor(rmax, 32, 64));
      float corr = 1.f;
      if (__any(rmax > mrow)) {
        const float mn = fmaxf(mrow, rmax);
        corr = exp2f((mrow - mn) * LOG2E);
        mrow = mn;
        #pragma unroll
        for (int nd = 0; nd < 4; ++nd)
          #pragma unroll
          for (int r = 0; r < 4; ++r) accO[nd][r] *= corr;
      }
      const float mb = mrow * LOG2E;
      float rsum = 0.f;
      #pragma unroll
      for (int n = 0; n < 4; ++n)
        #pragma unroll
        for (int r = 0; r < 4; ++r) {
          const float p = exp2f(fmaf(accS[n][r], LOG2E, -mb));
          accS[n][r] = p;
          rsum += p;
        }
      rsum += __shfl_xor(rsum, 16, 64);
      rsum += __shfl_xor(rsum, 32, 64);
      lrow = lrow * corr + rsum;
      #pragma unroll
      for (int n = 0; n < 4; ++n) {
        bf16x4 pk;
        #pragma unroll
        for (int r = 0; r < 4; ++r) pk[r] = (bf16_t)accS[n][r];
        *(bf16x4*)(&plds[wvi][l15 * 64 + ((4 * n + lhi) ^ psw) * 4]) = pk;
      }
      #pragma unroll
      for (int kk = 0; kk < 2; ++kk) {
        const bf16x8 pf = *(const bf16x8*)(&plds[wvi][l15 * 64 + ((8 * kk + 2 * lhi) ^ psw) * 4]);
        #pragma unroll
        for (int nd = 0; nd < 4; ++nd) {
          const bf16x8 vf = *(const bf16x8*)(Vb[cur] + (nd * 16 + l15) * 64 + ((kk * 4 + lhi) ^ sw) * 8);
          accO[nd] = __builtin_amdgcn_mfma_f32_16x16x32_bf16(vf, pf, accO[nd], 0, 0, 0);
        }
      }
      __syncthreads();
      cur ^= 1;
    }
    const float inv = 1.f / lrow;
    const long crow = (b * 2048 + qw0 + l15) * 1024 + hh * 64;
    #pragma unroll
    for (int nd = 0; nd < 4; ++nd) {
      bf16x4 ok;
      #pragma unroll
      for (int r = 0; r < 4; ++r) ok[r] = (bf16_t)(accO[nd][r] * inv);
      *(bf16x4*)(ctx + crow + nd * 16 + lhi * 4) = ok;
    }
  }
}

extern "C" void kernel_launch(void* const* d_in, const int* in_sizes, int n_in,
                              void* d_out, int out_size, void* d_ws, size_t ws_size,
                              hipStream_t stream)
{
  const float* x   = (const float*)d_in[0];
  const float* wq  = (const float*)d_in[1];
  const float* wk  = (const float*)d_in[2];
  const float* wv  = (const float*)d_in[3];
  const float* wo  = (const float*)d_in[4];
  const float* bo  = (const float*)d_in[5];
  const float* w1  = (const float*)d_in[6];
  const float* b1  = (const float*)d_in[7];
  const float* w2  = (const float*)d_in[8];
  const float* b2  = (const float*)d_in[9];
  const float* w3  = (const float*)d_in[10];
  const float* b3  = (const float*)d_in[11];
  const float* g1  = (const float*)d_in[12];
  const float* be1 = (const float*)d_in[13];
  const float* g2  = (const float*)d_in[14];
  const float* be2 = (const float*)d_in[15];
  float* out = (float*)d_out;

  char* ws = (char*)d_ws;
  bf16_t* h    = (bf16_t*)(ws);                          // 16 MiB (later: ctx)
  bf16_t* qb   = (bf16_t*)(ws + 16777216L);              // 16 MiB (later: h2)
  bf16_t* kb   = (bf16_t*)(ws + 2 * 16777216L);          // 16 MiB
  bf16_t* vTb  = (bf16_t*)(ws + 3 * 16777216L);          // 16 MiB
  bf16_t* r1b  = (bf16_t*)(ws + 4 * 16777216L);          // 16 MiB (bf16 residual)
  bf16_t* ffin = (bf16_t*)(ws + 4 * 16777216L + 33554432L); // 64 MiB
  char* wbase  = ws + 4 * 16777216L + 33554432L + 67108864L;
  bf16_t* Wqkvt = (bf16_t*)(wbase);                      // [3072][1024]
  bf16_t* Wot   = (bf16_t*)(wbase + 6291456L);           // [1024][1024]
  bf16_t* Wp    = (bf16_t*)(wbase + 8388608L);           // [8192][1024] packed W1|W2
  bf16_t* W3t   = (bf16_t*)(wbase + 25165824L);          // [1024][4096]

  const dim3 tb(64, 4);
  transpose_cvt<0><<<dim3(1, 16, 16), tb, 0, stream>>>(wq, Wqkvt,            1024, 64, 65536, 65536, 0, 0.125f);
  transpose_cvt<0><<<dim3(1, 16, 16), tb, 0, stream>>>(wk, Wqkvt + 1048576L, 1024, 64, 65536, 65536, 0, 1.0f);
  transpose_cvt<0><<<dim3(1, 16, 16), tb, 0, stream>>>(wv, Wqkvt + 2097152L, 1024, 64, 65536, 65536, 0, 1.0f);
  transpose_cvt<0><<<dim3(16, 16, 1), tb, 0, stream>>>(wo, Wot, 1024, 1024, 0, 0, 0, 1.0f);
  transpose_cvt<1><<<dim3(64, 16, 1), tb, 0, stream>>>(w1, Wp, 1024, 4096, 0, 0, 0, 1.0f);
  transpose_cvt<1><<<dim3(64, 16, 1), tb, 0, stream>>>(w2, Wp, 1024, 4096, 0, 0, 16, 1.0f);
  transpose_cvt<0><<<dim3(16, 64, 1), tb, 0, stream>>>(w3, W3t, 4096, 1024, 0, 0, 0, 1.0f);
  // LN1
  ln_kernel<0><<<8192, 256, 0, stream>>>(x, g1, be1, h);
  // QKV projection
  gemmU<0, 1024><<<dim3(24, 64), 256, 0, stream>>>(h, Wqkvt, nullptr, nullptr, nullptr, nullptr,
                                                   nullptr, nullptr, qb, kb, vTb, 3072);
  // attention -> ctx (reuses h)
  attn_kernel<<<dim3(64, 16), 256, 0, stream>>>(qb, kb, vTb, h);
  // r1b (bf16) = x + ctx @ Wo + bo
  gemmU<1, 1024><<<dim3(8, 64), 256, 0, stream>>>(h, Wot, bo, nullptr, x, nullptr,
                                                  nullptr, r1b, nullptr, nullptr, nullptr, 1024);
  // LN2 -> h2 (reuses qb)
  ln_kernel<1><<<8192, 256, 0, stream>>>(r1b, g2, be2, qb);
  // ffin = silu(h2@W1+b1) * (h2@W2+b2)  -- packed dual, logical N = 4096
  gemmU<3, 1024><<<dim3(64, 64), 256, 0, stream>>>(qb, Wp, b1, b2, nullptr, nullptr,
                                                   nullptr, ffin, nullptr, nullptr, nullptr, 4096);
  // out (fp32) = r1b + ffin @ w3 + b3
  gemmU<2, 4096><<<dim3(8, 64), 256, 0, stream>>>(ffin, W3t, b3, nullptr, nullptr, r1b,
                                                  out, nullptr, nullptr, nullptr, nullptr, 1024);
}

// Round 20
// 450.802 us; speedup vs baseline: 1.0638x; 1.0502x over previous
//
#include <hip/hip_runtime.h>
#include <hip/hip_bf16.h>
#include <cstdint>

// Block: B=4, S=2048, E=1024, H=16, DH=64, DF=4096.  M = B*S = 8192 rows.
// All GEMMs: unified gemmU -- 128x128 tile, BK=64, 4 waves (2Mx2N) of 64x64,
// reg-cached fragments, 8-chunk XOR swizzle (0 conflicts), dbuf 64 KB ->
// 2 blocks/CU.  FFN B = W1|W2 16-col interleave (SwiGLU fused).
// Attention: 4-wave 64-row kernel (R17 best), K/V LDS-staged, 4 blocks/CU;
// scale-folded-into-Wq, defer-max skip, fma-folded exp2, tree max-reduce.
// R20: QKV epilogue V-store vectorized (bf16x4 along r; addresses contiguous
// in s for the transposed [B,H,DH,S] layout).

typedef __bf16 bf16_t;
typedef __attribute__((ext_vector_type(8))) __bf16 bf16x8;
typedef __attribute__((ext_vector_type(4))) __bf16 bf16x4;
typedef __attribute__((ext_vector_type(4))) float f32x4;

#define LOG2E 1.4426950408889634f

static __device__ __forceinline__ void gll16(const void* g, void* l) {
  __builtin_amdgcn_global_load_lds(
      (const __attribute__((address_space(1))) void*)g,
      (__attribute__((address_space(3))) void*)l, 16, 0, 0);
}

// ---------------- transpose + fp32->bf16 convert (+optional scale) ---------
template<int PACK>
__global__ __launch_bounds__(256)
void transpose_cvt(const float* __restrict__ in, bf16_t* __restrict__ out,
                   int R, int C, long in_batch, long out_batch, int off,
                   float scale)
{
  __shared__ float tile[64][65];
  const float* inp = in + (long)blockIdx.z * in_batch;
  bf16_t* outp = out + (long)blockIdx.z * out_batch;
  const int c0 = blockIdx.x * 64, r0 = blockIdx.y * 64;
  for (int rr = threadIdx.y; rr < 64; rr += 4)
    tile[rr][threadIdx.x] = inp[(long)(r0 + rr) * C + c0 + threadIdx.x];
  __syncthreads();
  for (int cc = threadIdx.y; cc < 64; cc += 4) {
    const int c = c0 + cc;
    const long orow = PACK ? (long)((c >> 4) * 32 + (c & 15) + off) : (long)c;
    outp[orow * R + r0 + threadIdx.x] = (bf16_t)(tile[threadIdx.x][cc] * scale);
  }
}

// ---------------- LayerNorm (fp32/bf16 in, bf16 out) ----------------
template<int BF16IN>
__global__ __launch_bounds__(256)
void ln_kernel(const void* __restrict__ xin, const float* __restrict__ g,
               const float* __restrict__ be, bf16_t* __restrict__ out)
{
  const long row = blockIdx.x;
  float e0, e1, e2, e3;
  if constexpr (BF16IN) {
    const bf16x4 v = ((const bf16x4*)((const bf16_t*)xin + row * 1024))[threadIdx.x];
    e0 = (float)v[0]; e1 = (float)v[1]; e2 = (float)v[2]; e3 = (float)v[3];
  } else {
    const float4 v = ((const float4*)((const float*)xin + row * 1024))[threadIdx.x];
    e0 = v.x; e1 = v.y; e2 = v.z; e3 = v.w;
  }
  float s  = e0 + e1 + e2 + e3;
  float s2 = e0*e0 + e1*e1 + e2*e2 + e3*e3;
  #pragma unroll
  for (int m = 1; m < 64; m <<= 1) {
    s  += __shfl_xor(s, m, 64);
    s2 += __shfl_xor(s2, m, 64);
  }
  __shared__ float red[8];
  const int w = threadIdx.x >> 6, lane = threadIdx.x & 63;
  if (lane == 0) { red[w] = s; red[4 + w] = s2; }
  __syncthreads();
  s  = red[0] + red[1] + red[2] + red[3];
  s2 = red[4] + red[5] + red[6] + red[7];
  const float mu = s * (1.f / 1024.f);
  const float rs = rsqrtf(s2 * (1.f / 1024.f) - mu * mu + 1e-5f);
  const int c = threadIdx.x * 4;
  bf16x4 o;
  o[0] = (bf16_t)((e0 - mu) * rs * g[c+0] + be[c+0]);
  o[1] = (bf16_t)((e1 - mu) * rs * g[c+1] + be[c+1]);
  o[2] = (bf16_t)((e2 - mu) * rs * g[c+2] + be[c+2]);
  o[3] = (bf16_t)((e3 - mu) * rs * g[c+3] + be[c+3]);
  *(bf16x4*)(out + row * 1024 + c) = o;
}

// ================= unified 128x128 GEMM, BK=64, 4 waves, 2 blocks/CU =======
template<int EPI, int KT>
__global__ __launch_bounds__(256, 2)
void gemmU(const bf16_t* __restrict__ A, const bf16_t* __restrict__ Bt,
           const float* __restrict__ bias, const float* __restrict__ bias2,
           const float* __restrict__ resF, const bf16_t* __restrict__ resB,
           float* __restrict__ outF, bf16_t* __restrict__ outB,
           bf16_t* __restrict__ outQ, bf16_t* __restrict__ outK, bf16_t* __restrict__ outV,
           int N)
{
  __shared__ __align__(16) bf16_t Asl[2][128 * 64];
  __shared__ __align__(16) bf16_t Bsl[2][128 * 64];
  constexpr int NT = KT / 64;
  const int tid = threadIdx.x, lane = tid & 63;
  const int w = tid >> 6, wr = w >> 1, wc = w & 1;
  const long row0 = (long)blockIdx.y * 128;
  const long col0 = (long)blockIdx.x * 128;
  const int l15 = lane & 15, lhi = lane >> 4;
  const int offk0 = ((lhi ^ (l15 & 7)) & 7) * 8;   // swizzled chunk, ks=0
  f32x4 acc[4][4] = {};

  auto stage = [&](int t, int buf) {     // 8 gll16/thread: A 16KB + B 16KB
    const long k0 = (long)t * 64;
    #pragma unroll
    for (int i = 0; i < 4; ++i) {
      const int p = tid + 256 * i;
      const int r = p >> 3, cl = (p & 7) ^ (r & 7);
      gll16(A + (row0 + r) * (long)KT + k0 + cl * 8, (char*)Asl[buf] + p * 16);
    }
    #pragma unroll
    for (int i = 0; i < 4; ++i) {
      const int p = tid + 256 * i;
      const int r = p >> 3, cl = (p & 7) ^ (r & 7);
      gll16(Bt + (col0 + r) * (long)KT + k0 + cl * 8, (char*)Bsl[buf] + p * 16);
    }
  };

  stage(0, 0);
  __syncthreads();
  int cur = 0;
  for (int t = 0; t < NT; ++t) {
    if (t + 1 < NT) stage(t + 1, cur ^ 1);
    bf16x8 af[4][2], bfr[4][2];
    const bf16_t* ap = Asl[cur] + (wr * 64 + l15) * 64;
    const bf16_t* bp = Bsl[cur] + (wc * 64 + l15) * 64;
    #pragma unroll
    for (int m = 0; m < 4; ++m) {
      af[m][0] = *(const bf16x8*)(ap + m * 16 * 64 + offk0);
      af[m][1] = *(const bf16x8*)(ap + m * 16 * 64 + (offk0 ^ 32));
    }
    #pragma unroll
    for (int n = 0; n < 4; ++n) {
      bfr[n][0] = *(const bf16x8*)(bp + n * 16 * 64 + offk0);
      bfr[n][1] = *(const bf16x8*)(bp + n * 16 * 64 + (offk0 ^ 32));
    }
    __builtin_amdgcn_s_setprio(1);
    #pragma unroll
    for (int m = 0; m < 4; ++m)
      #pragma unroll
      for (int n = 0; n < 4; ++n)
        #pragma unroll
        for (int ks = 0; ks < 2; ++ks)
          acc[m][n] = __builtin_amdgcn_mfma_f32_16x16x32_bf16(
              af[m][ks], bfr[n][ks], acc[m][n], 0, 0, 0);
    __builtin_amdgcn_s_setprio(0);
    __syncthreads();
    cur ^= 1;
  }

  if constexpr (EPI == 3) {
    const long L0 = ((col0 + wc * 64) >> 5) * 16;
    #pragma unroll
    for (int m = 0; m < 4; ++m) {
      #pragma unroll
      for (int np = 0; np < 2; ++np) {
        const long lc = L0 + np * 16 + l15;
        #pragma unroll
        for (int r = 0; r < 4; ++r) {
          const long rr = row0 + wr * 64 + m * 16 + lhi * 4 + r;
          const float a  = acc[m][2 * np][r] + bias[lc];
          const float gt = acc[m][2 * np + 1][r] + bias2[lc];
          const float sig = 1.0f / (1.0f + __expf(-a));
          outB[rr * N + lc] = (bf16_t)(a * sig * gt);
        }
      }
    }
  } else if constexpr (EPI == 0) {
    #pragma unroll
    for (int m = 0; m < 4; ++m) {
      #pragma unroll
      for (int n = 0; n < 4; ++n) {
        const long cc = col0 + wc * 64 + n * 16 + l15;
        const int which = (int)(cc >> 10);
        const int hh = (int)((cc >> 6) & 15);
        const int d  = (int)(cc & 63);
        const long rr0 = row0 + wr * 64 + m * 16 + lhi * 4;
        const long b = rr0 >> 11, s0 = rr0 & 2047;   // 4 consecutive s values
        const long bh = b * 16 + hh;
        if (which == 2) {
          // V transposed [B,H,DH,S]: addresses contiguous in s -> one 8B store
          bf16x4 vv;
          #pragma unroll
          for (int r = 0; r < 4; ++r) vv[r] = (bf16_t)acc[m][n][r];
          *(bf16x4*)(outV + (bh * 64 + d) * 2048 + s0) = vv;
        } else {
          bf16_t* dst = (which == 0) ? outQ : outK;
          #pragma unroll
          for (int r = 0; r < 4; ++r)
            dst[(bh * 2048 + s0 + r) * 64 + d] = (bf16_t)acc[m][n][r];
        }
      }
    }
  } else {
    #pragma unroll
    for (int m = 0; m < 4; ++m) {
      #pragma unroll
      for (int n = 0; n < 4; ++n) {
        const long cc = col0 + wc * 64 + n * 16 + l15;
        #pragma unroll
        for (int r = 0; r < 4; ++r) {
          const long rr = row0 + wr * 64 + m * 16 + lhi * 4 + r;
          const float v = acc[m][n][r];
          if constexpr (EPI == 1) {
            outB[rr * N + cc] = (bf16_t)(v + bias[cc] + resF[rr * N + cc]);
          } else {
            outF[rr * N + cc] = v + bias[cc] + (float)resB[rr * N + cc];
          }
        }
      }
    }
  }
}

// ---------------- causal flash attention v4.2 (R17 best) -------------------
__global__ __launch_bounds__(256, 4)
void attn_kernel(const bf16_t* __restrict__ q, const bf16_t* __restrict__ k,
                 const bf16_t* __restrict__ vT, bf16_t* __restrict__ ctx)
{
  __shared__ __align__(16) bf16_t Kb[2][64 * 64];
  __shared__ __align__(16) bf16_t Vb[2][64 * 64];
  __shared__ __align__(16) bf16_t plds[4][16 * 64];
  const int tid = threadIdx.x, lane = tid & 63, wvi = tid >> 6;
  const int bh = blockIdx.x;
  const bf16_t* qp = q  + (long)bh * 2048 * 64;
  const bf16_t* kp = k  + (long)bh * 2048 * 64;
  const bf16_t* vp = vT + (long)bh * 64 * 2048;
  const int l15 = lane & 15, lhi = lane >> 4;
  const long b = bh >> 4;
  const int hh = bh & 15;
  const int sw = (l15 & 7);
  const int psw = sw << 1;

  const int r0s = tid >> 3, cl0 = (tid & 7) ^ (r0s & 7);
  const int r1s = (tid + 256) >> 3, cl1 = (tid & 7) ^ (r1s & 7);

  #pragma unroll
  for (int seg = 0; seg < 2; ++seg) {
    const int ts = (seg == 0) ? blockIdx.y : 31 - blockIdx.y;
    const int qw0 = ts * 64 + wvi * 16;
    const int q_glob = qw0 + l15;
    bf16x8 qf[2];
    #pragma unroll
    for (int kk = 0; kk < 2; ++kk)
      qf[kk] = *(const bf16x8*)(qp + (long)(qw0 + l15) * 64 + kk * 32 + lhi * 8);
    f32x4 accO[4] = {};
    float mrow = -1e30f, lrow = 0.f;

    gll16(kp + (long)(0 + r0s) * 64 + cl0 * 8, (char*)Kb[0] + tid * 16);
    gll16(vp + (long)r0s * 2048 + 0 + cl0 * 8, (char*)Vb[0] + tid * 16);
    gll16(kp + (long)(0 + r1s) * 64 + cl1 * 8, (char*)Kb[0] + (tid + 256) * 16);
    gll16(vp + (long)r1s * 2048 + 0 + cl1 * 8, (char*)Vb[0] + (tid + 256) * 16);
    __syncthreads();

    int cur = 0;
    const int kbmax = ts * 64;
    for (int kb = 0; kb <= kbmax; kb += 64) {
      if (kb + 64 <= kbmax) {
        const int nb = kb + 64;
        gll16(kp + (long)(nb + r0s) * 64 + cl0 * 8, (char*)Kb[cur ^ 1] + tid * 16);
        gll16(vp + (long)r0s * 2048 + nb + cl0 * 8, (char*)Vb[cur ^ 1] + tid * 16);
        gll16(kp + (long)(nb + r1s) * 64 + cl1 * 8, (char*)Kb[cur ^ 1] + (tid + 256) * 16);
        gll16(vp + (long)r1s * 2048 + nb + cl1 * 8, (char*)Vb[cur ^ 1] + (tid + 256) * 16);
      }
      f32x4 accS[4] = {};
      #pragma unroll
      for (int n = 0; n < 4; ++n) {
        const bf16_t* kr = Kb[cur] + (n * 16 + l15) * 64;
        #pragma unroll
        for (int kk = 0; kk < 2; ++kk) {
          const bf16x8 kf = *(const bf16x8*)(kr + ((kk * 4 + lhi) ^ sw) * 8);
          accS[n] = __builtin_amdgcn_mfma_f32_16x16x32_bf16(kf, qf[kk], accS[n], 0, 0, 0);
        }
      }
      const bool needmask = (kb + 63 > qw0);
      if (needmask) {
        #pragma unroll
        for (int n = 0; n < 4; ++n)
          #pragma unroll
          for (int r = 0; r < 4; ++r)
            if (kb + n * 16 + lhi * 4 + r > q_glob) accS[n][r] = -1e30f;
      }
      float t0 = fmaxf(fmaxf(accS[0][0], accS[0][1]), fmaxf(accS[0][2], accS[0][3]));
      float t1 = fmaxf(fmaxf(accS[1][0], accS[1][1]), fmaxf(accS[1][2], accS[1][3]));
      float t2 = fmaxf(fmaxf(accS[2][0], accS[2][1]), fmaxf(accS[2][2], accS[2][3]));
      float t3 = fmaxf(fmaxf(accS[3][0], accS[3][1]), fmaxf(accS[3][2], accS[3][3]));
      float rmax = fmaxf(fmaxf(t0, t1), fmaxf(t2, t3));
      rmax = fmaxf(rmax, __shfl_xor(rmax, 16, 64));
      rmax = fmaxf(rmax, __shfl_xor(rmax, 32, 64));
      float corr = 1.f;
      if (__any(rmax > mrow)) {
        const float mn = fmaxf(mrow, rmax);
        corr = exp2f((mrow - mn) * LOG2E);
        mrow = mn;
        #pragma unroll
        for (int nd = 0; nd < 4; ++nd)
          #pragma unroll
          for (int r = 0; r < 4; ++r) accO[nd][r] *= corr;
      }
      const float mb = mrow * LOG2E;
      float rsum = 0.f;
      #pragma unroll
      for (int n = 0; n < 4; ++n)
        #pragma unroll
        for (int r = 0; r < 4; ++r) {
          const float p = exp2f(fmaf(accS[n][r], LOG2E, -mb));
          accS[n][r] = p;
          rsum += p;
        }
      rsum += __shfl_xor(rsum, 16, 64);
      rsum += __shfl_xor(rsum, 32, 64);
      lrow = lrow * corr + rsum;
      #pragma unroll
      for (int n = 0; n < 4; ++n) {
        bf16x4 pk;
        #pragma unroll
        for (int r = 0; r < 4; ++r) pk[r] = (bf16_t)accS[n][r];
        *(bf16x4*)(&plds[wvi][l15 * 64 + ((4 * n + lhi) ^ psw) * 4]) = pk;
      }
      #pragma unroll
      for (int kk = 0; kk < 2; ++kk) {
        const bf16x8 pf = *(const bf16x8*)(&plds[wvi][l15 * 64 + ((8 * kk + 2 * lhi) ^ psw) * 4]);
        #pragma unroll
        for (int nd = 0; nd < 4; ++nd) {
          const bf16x8 vf = *(const bf16x8*)(Vb[cur] + (nd * 16 + l15) * 64 + ((kk * 4 + lhi) ^ sw) * 8);
          accO[nd] = __builtin_amdgcn_mfma_f32_16x16x32_bf16(vf, pf, accO[nd], 0, 0, 0);
        }
      }
      __syncthreads();
      cur ^= 1;
    }
    const float inv = 1.f / lrow;
    const long crow = (b * 2048 + qw0 + l15) * 1024 + hh * 64;
    #pragma unroll
    for (int nd = 0; nd < 4; ++nd) {
      bf16x4 ok;
      #pragma unroll
      for (int r = 0; r < 4; ++r) ok[r] = (bf16_t)(accO[nd][r] * inv);
      *(bf16x4*)(ctx + crow + nd * 16 + lhi * 4) = ok;
    }
  }
}

extern "C" void kernel_launch(void* const* d_in, const int* in_sizes, int n_in,
                              void* d_out, int out_size, void* d_ws, size_t ws_size,
                              hipStream_t stream)
{
  const float* x   = (const float*)d_in[0];
  const float* wq  = (const float*)d_in[1];
  const float* wk  = (const float*)d_in[2];
  const float* wv  = (const float*)d_in[3];
  const float* wo  = (const float*)d_in[4];
  const float* bo  = (const float*)d_in[5];
  const float* w1  = (const float*)d_in[6];
  const float* b1  = (const float*)d_in[7];
  const float* w2  = (const float*)d_in[8];
  const float* b2  = (const float*)d_in[9];
  const float* w3  = (const float*)d_in[10];
  const float* b3  = (const float*)d_in[11];
  const float* g1  = (const float*)d_in[12];
  const float* be1 = (const float*)d_in[13];
  const float* g2  = (const float*)d_in[14];
  const float* be2 = (const float*)d_in[15];
  float* out = (float*)d_out;

  char* ws = (char*)d_ws;
  bf16_t* h    = (bf16_t*)(ws);                          // 16 MiB (later: ctx)
  bf16_t* qb   = (bf16_t*)(ws + 16777216L);              // 16 MiB (later: h2)
  bf16_t* kb   = (bf16_t*)(ws + 2 * 16777216L);          // 16 MiB
  bf16_t* vTb  = (bf16_t*)(ws + 3 * 16777216L);          // 16 MiB
  bf16_t* r1b  = (bf16_t*)(ws + 4 * 16777216L);          // 16 MiB (bf16 residual)
  bf16_t* ffin = (bf16_t*)(ws + 4 * 16777216L + 33554432L); // 64 MiB
  char* wbase  = ws + 4 * 16777216L + 33554432L + 67108864L;
  bf16_t* Wqkvt = (bf16_t*)(wbase);                      // [3072][1024]
  bf16_t* Wot   = (bf16_t*)(wbase + 6291456L);           // [1024][1024]
  bf16_t* Wp    = (bf16_t*)(wbase + 8388608L);           // [8192][1024] packed W1|W2
  bf16_t* W3t   = (bf16_t*)(wbase + 25165824L);          // [1024][4096]

  const dim3 tb(64, 4);
  transpose_cvt<0><<<dim3(1, 16, 16), tb, 0, stream>>>(wq, Wqkvt,            1024, 64, 65536, 65536, 0, 0.125f);
  transpose_cvt<0><<<dim3(1, 16, 16), tb, 0, stream>>>(wk, Wqkvt + 1048576L, 1024, 64, 65536, 65536, 0, 1.0f);
  transpose_cvt<0><<<dim3(1, 16, 16), tb, 0, stream>>>(wv, Wqkvt + 2097152L, 1024, 64, 65536, 65536, 0, 1.0f);
  transpose_cvt<0><<<dim3(16, 16, 1), tb, 0, stream>>>(wo, Wot, 1024, 1024, 0, 0, 0, 1.0f);
  transpose_cvt<1><<<dim3(64, 16, 1), tb, 0, stream>>>(w1, Wp, 1024, 4096, 0, 0, 0, 1.0f);
  transpose_cvt<1><<<dim3(64, 16, 1), tb, 0, stream>>>(w2, Wp, 1024, 4096, 0, 0, 16, 1.0f);
  transpose_cvt<0><<<dim3(16, 64, 1), tb, 0, stream>>>(w3, W3t, 4096, 1024, 0, 0, 0, 1.0f);
  // LN1
  ln_kernel<0><<<8192, 256, 0, stream>>>(x, g1, be1, h);
  // QKV projection
  gemmU<0, 1024><<<dim3(24, 64), 256, 0, stream>>>(h, Wqkvt, nullptr, nullptr, nullptr, nullptr,
                                                   nullptr, nullptr, qb, kb, vTb, 3072);
  // attention -> ctx (reuses h)
  attn_kernel<<<dim3(64, 16), 256, 0, stream>>>(qb, kb, vTb, h);
  // r1b (bf16) = x + ctx @ Wo + bo
  gemmU<1, 1024><<<dim3(8, 64), 256, 0, stream>>>(h, Wot, bo, nullptr, x, nullptr,
                                                  nullptr, r1b, nullptr, nullptr, nullptr, 1024);
  // LN2 -> h2 (reuses qb)
  ln_kernel<1><<<8192, 256, 0, stream>>>(r1b, g2, be2, qb);
  // ffin = silu(h2@W1+b1) * (h2@W2+b2)  -- packed dual, logical N = 4096
  gemmU<3, 1024><<<dim3(64, 64), 256, 0, stream>>>(qb, Wp, b1, b2, nullptr, nullptr,
                                                   nullptr, ffin, nullptr, nullptr, nullptr, 4096);
  // out (fp32) = r1b + ffin @ w3 + b3
  gemmU<2, 4096><<<dim3(8, 64), 256, 0, stream>>>(ffin, W3t, b3, nullptr, nullptr, r1b,
                                                  out, nullptr, nullptr, nullptr, nullptr, 1024);
}